// Round 1
// baseline (416.085 us; speedup 1.0000x reference)
//
#include <hip/hip_runtime.h>
#include <hip/hip_bf16.h>
#include <cstdint>
#include <cstddef>

// Problem constants
#define BB   128   // batch
#define SS   128   // set size
#define GG   2000  // genes (K of input proj)
#define NHID 256   // n_hidden
#define NHEAD 4
#define HDIM 64
#define NLAT 64

typedef __attribute__((ext_vector_type(4))) float f32x4;
typedef __attribute__((ext_vector_type(8))) short short8;
typedef __attribute__((ext_vector_type(8))) __bf16 bf8_t;

static __device__ __forceinline__ bf8_t as_bf8(short8 s){
  union { short8 s; bf8_t b; } u; u.s = s; return u.b;
}

static __device__ __forceinline__ unsigned short f2bf(float f){
  union { float f; unsigned u; } x; x.f = f;
  unsigned r = x.u + 0x7fffu + ((x.u >> 16) & 1u);
  return (unsigned short)(r >> 16);
}

// ---------------------------------------------------------------------------
// Transpose + convert + zero-pad: W (K x N, f32 row-major) -> Wt (N x Kpad, bf16)
// ---------------------------------------------------------------------------
__global__ __launch_bounds__(256) void k_transconv(
    const float* __restrict__ W, unsigned short* __restrict__ Wt,
    int K, int N, int Kpad)
{
  int idx = blockIdx.x * 256 + threadIdx.x;
  if (idx >= N * Kpad) return;
  int n = idx / Kpad, k = idx - n * Kpad;
  float v = (k < K) ? W[(size_t)k * N + n] : 0.f;
  Wt[idx] = f2bf(v);
}

// ---------------------------------------------------------------------------
// bf16 MFMA GEMM: Out[M x 256] = A[M x Kvalid](f32, lda) @ Bt^T + bias
//   Bt is (256 x ldb) bf16, pre-transposed (row n holds column n of B), padded.
//   BM=128, BN=256(full), BK=32. 512 threads = 8 waves (2x4), wave = 64x64.
// ---------------------------------------------------------------------------
__global__ __launch_bounds__(512, 1) void k_gemm(
    const float* __restrict__ A, int lda, int Kvalid, int nsteps,
    const unsigned short* __restrict__ Bt, int ldb,
    const float* __restrict__ bias, float* __restrict__ Out)
{
  __shared__ __align__(16) unsigned short Abuf[2][8 * 64 * 8];   // frag-major
  __shared__ __align__(16) unsigned short Bbuf[2][16 * 64 * 8];  // frag-major
  const int tid  = threadIdx.x;
  const int m0   = blockIdx.x * 128;
  const int lane = tid & 63;
  const int w    = tid >> 6;
  const int wr   = w >> 2, wc = w & 3;

  f32x4 acc[4][4];
#pragma unroll
  for (int i = 0; i < 4; ++i)
#pragma unroll
    for (int j = 0; j < 4; ++j) acc[i][j] = (f32x4)(0.f);

  // staging roles
  const int arow = tid >> 2, akg = tid & 3;   // A: 128 rows x 4 k-groups of 8
  const int bn   = tid >> 1, bkh = tid & 1;   // B: 256 cols x 2 k-halves of 16
  const float* aptr = A + (size_t)(m0 + arow) * lda + akg * 8;
  const unsigned short* bptr = Bt + (size_t)bn * ldb + bkh * 16;
  unsigned short* adst  = &Abuf[0][(((arow >> 4) << 6) | (akg << 4) | (arow & 15)) * 8];
  unsigned short* bdst  = &Bbuf[0][(((bn >> 4) << 6) | (bkh << 5) | (bn & 15)) * 8];

  auto stage = [&](int buf, int kbase) {
    float v[8];
    if (kbase + akg * 8 + 8 <= Kvalid) {
      f32x4 a0 = *(const f32x4*)(aptr + kbase);
      f32x4 a1 = *(const f32x4*)(aptr + kbase + 4);
      v[0] = a0.x; v[1] = a0.y; v[2] = a0.z; v[3] = a0.w;
      v[4] = a1.x; v[5] = a1.y; v[6] = a1.z; v[7] = a1.w;
    } else {
#pragma unroll
      for (int t = 0; t < 8; ++t) v[t] = 0.f;
    }
    short8 av;
#pragma unroll
    for (int t = 0; t < 8; ++t) av[t] = (short)f2bf(v[t]);
    *(short8*)(adst + (size_t)buf * (8 * 64 * 8)) = av;

    short8 b0 = *(const short8*)(bptr + kbase);
    short8 b1 = *(const short8*)(bptr + kbase + 8);
    *(short8*)(bdst + (size_t)buf * (16 * 64 * 8)) = b0;
    *(short8*)(bdst + (size_t)buf * (16 * 64 * 8) + 128) = b1;
  };

  stage(0, 0);
  __syncthreads();

  const unsigned short* abase = &Abuf[0][((wr << 2) * 64 + lane) * 8];
  const unsigned short* bbase = &Bbuf[0][((wc << 2) * 64 + lane) * 8];

  for (int s = 0; s < nsteps; ++s) {
    const int cur = s & 1;
    if (s + 1 < nsteps) stage(cur ^ 1, (s + 1) * 32);
    short8 af[4], bfv[4];
    const unsigned short* ab = abase + (size_t)cur * (8 * 64 * 8);
    const unsigned short* bb = bbase + (size_t)cur * (16 * 64 * 8);
#pragma unroll
    for (int i = 0; i < 4; ++i) af[i]  = *(const short8*)(ab + i * 64 * 8);
#pragma unroll
    for (int j = 0; j < 4; ++j) bfv[j] = *(const short8*)(bb + j * 64 * 8);
#pragma unroll
    for (int i = 0; i < 4; ++i)
#pragma unroll
      for (int j = 0; j < 4; ++j)
        acc[i][j] = __builtin_amdgcn_mfma_f32_16x16x32_bf16(
            as_bf8(af[i]), as_bf8(bfv[j]), acc[i][j], 0, 0, 0);
    __syncthreads();
  }

  const int orow = m0 + (wr << 6) + ((lane >> 4) << 2);
  const int ocol = (wc << 6) + (lane & 15);
#pragma unroll
  for (int j = 0; j < 4; ++j) {
    const int col = ocol + j * 16;
    const float bv = bias ? bias[col] : 0.f;
#pragma unroll
    for (int i = 0; i < 4; ++i) {
      const int row = orow + i * 16;
#pragma unroll
      for (int r = 0; r < 4; ++r)
        Out[(size_t)(row + r) * NHID + col] = acc[i][j][r] + bv;
    }
  }
}

// ---------------------------------------------------------------------------
// Row LayerNorm (N=256) + optional exact GELU. One wave per row.
// ---------------------------------------------------------------------------
__global__ __launch_bounds__(256, 1) void k_ln_gelu(
    const float* __restrict__ X, const float* __restrict__ g,
    const float* __restrict__ b, float* __restrict__ Y, int do_gelu)
{
  const int l   = threadIdx.x & 63;
  const int row = blockIdx.x * 4 + (threadIdx.x >> 6);
  f32x4 v = *(const f32x4*)(X + (size_t)row * NHID + l * 4);
  float s  = v.x + v.y + v.z + v.w;
  float sq = v.x * v.x + v.y * v.y + v.z * v.z + v.w * v.w;
#pragma unroll
  for (int m = 1; m < 64; m <<= 1) { s += __shfl_xor(s, m); sq += __shfl_xor(sq, m); }
  float mu   = s * (1.f / 256.f);
  float var  = sq * (1.f / 256.f) - mu * mu;
  float rstd = rsqrtf(var + 1e-5f);
  f32x4 gg = *(const f32x4*)(g + l * 4);
  f32x4 bb = *(const f32x4*)(b + l * 4);
  f32x4 o;
#pragma unroll
  for (int t = 0; t < 4; ++t) {
    float y = (v[t] - mu) * rstd * gg[t] + bb[t];
    if (do_gelu) y = 0.5f * y * (1.f + erff(y * 0.70710678118654752f));
    o[t] = y;
  }
  *(f32x4*)(Y + (size_t)row * NHID + l * 4) = o;
}

// ---------------------------------------------------------------------------
// Fold a_src/a_dst/a_edge into 256x4 matrices:
//   u1[k][h] = sum_d Wg[k][h*64+d]*a_src[h][d] + sum_d We[k][h*64+d]*a_edge[h][d]
//   u2[k][h] = sum_d Wg[k][h*64+d]*a_dst[h][d] - sum_d We[k][h*64+d]*a_edge[h][d]
// ---------------------------------------------------------------------------
__global__ __launch_bounds__(256, 1) void k_proj(
    const float* __restrict__ Wgl, const float* __restrict__ Wel,
    const float* __restrict__ asrc, const float* __restrict__ adst,
    const float* __restrict__ aedge, float* __restrict__ u1, float* __restrict__ u2)
{
  const int k = threadIdx.x;
#pragma unroll
  for (int h = 0; h < 4; ++h) {
    float ss = 0.f, sd = 0.f, se = 0.f;
    const float* wg  = Wgl + k * NHID + h * 64;
    const float* we  = Wel + k * NHID + h * 64;
    const float* pas = asrc + h * 64;
    const float* pad_ = adst + h * 64;
    const float* pae = aedge + h * 64;
#pragma unroll 4
    for (int d = 0; d < 64; ++d) {
      ss += wg[d] * pas[d];
      sd += wg[d] * pad_[d];
      se += we[d] * pae[d];
    }
    u1[k * 4 + h] = ss + se;
    u2[k * 4 + h] = sd - se;
  }
}

// ---------------------------------------------------------------------------
// Scores: c1 = h @ u1, c2 = h @ u2   (16384 x 4 each). One wave per row.
// ---------------------------------------------------------------------------
__global__ __launch_bounds__(256, 1) void k_scores(
    const float* __restrict__ hmat, const float* __restrict__ u1,
    const float* __restrict__ u2, float* __restrict__ c1, float* __restrict__ c2)
{
  __shared__ float su1[1024], su2[1024];
  const int tid = threadIdx.x;
  ((f32x4*)su1)[tid] = ((const f32x4*)u1)[tid];
  ((f32x4*)su2)[tid] = ((const f32x4*)u2)[tid];
  __syncthreads();
  const int w = tid >> 6, l = tid & 63;
  const int row = blockIdx.x * 4 + w;
  f32x4 hv = *(const f32x4*)(hmat + (size_t)row * NHID + l * 4);
#pragma unroll
  for (int h = 0; h < 4; ++h) {
    float d1 = hv.x * su1[(l * 4 + 0) * 4 + h] + hv.y * su1[(l * 4 + 1) * 4 + h]
             + hv.z * su1[(l * 4 + 2) * 4 + h] + hv.w * su1[(l * 4 + 3) * 4 + h];
    float d2 = hv.x * su2[(l * 4 + 0) * 4 + h] + hv.y * su2[(l * 4 + 1) * 4 + h]
             + hv.z * su2[(l * 4 + 2) * 4 + h] + hv.w * su2[(l * 4 + 3) * 4 + h];
#pragma unroll
    for (int mm = 1; mm < 64; mm <<= 1) { d1 += __shfl_xor(d1, mm); d2 += __shfl_xor(d2, mm); }
    if (l == 0) { c1[row * 4 + h] = d1; c2[row * 4 + h] = d2; }
  }
}

// ---------------------------------------------------------------------------
// GAT attention, one block per (head, batch). S=128, HD=64.
//   logits[i][j] = leaky(c1[i]+c2[j]); mask adj==0; softmax_j; out = P @ hp.
// hp tile staged in LDS, XOR-swizzled so PV reads are broadcast/conflict-free.
// ---------------------------------------------------------------------------
__global__ __launch_bounds__(256, 1) void k_attn(
    const float* __restrict__ hp, const float* __restrict__ c1,
    const float* __restrict__ c2, const int* __restrict__ adj,
    float* __restrict__ out)
{
  __shared__ __align__(16) float hp_t[64 * 128];   // [d][j] swizzled
  __shared__ float s1[128], s2[128];
  __shared__ __align__(16) float pbuf[4][8][128];
  const int head = blockIdx.x, b = blockIdx.y;
  const int tid = threadIdx.x, w = tid >> 6, l = tid & 63;

  if (tid < 128) {
    int m = b * SS + tid;
    s1[tid] = c1[m * 4 + head];
    s2[tid] = c2[m * 4 + head];
  }
  const float* hpb = hp + (size_t)b * SS * NHID + head * 64 + l;
#pragma unroll 4
  for (int rep = 0; rep < 32; ++rep) {
    int j = w * 32 + rep;
    float v = hpb[(size_t)j * NHID];
    hp_t[l * 128 + (((j >> 2) ^ (l & 7)) << 2) + (j & 3)] = v;
  }
  __syncthreads();

  const int* adjb = adj + (size_t)b * SS * SS;
  for (int pass = 0; pass < 4; ++pass) {
    const int ibase = w * 32 + pass * 8;
#pragma unroll
    for (int r = 0; r < 8; ++r) {
      const int i = ibase + r;
      float s1v = s1[i];
      float x1 = s1v + s2[l];
      float x2 = s1v + s2[l + 64];
      x1 = x1 >= 0.f ? x1 : 0.2f * x1;
      x2 = x2 >= 0.f ? x2 : 0.2f * x2;
      int a1 = adjb[i * SS + l];
      int a2 = adjb[i * SS + 64 + l];
      float m1 = a1 ? x1 : -3.0e38f;
      float m2 = a2 ? x2 : -3.0e38f;
      float mx = fmaxf(m1, m2);
#pragma unroll
      for (int mm = 1; mm < 64; mm <<= 1) mx = fmaxf(mx, __shfl_xor(mx, mm));
      float p1 = a1 ? expf(x1 - mx) : 0.f;
      float p2 = a2 ? expf(x2 - mx) : 0.f;
      float sum = p1 + p2;
#pragma unroll
      for (int mm = 1; mm < 64; mm <<= 1) sum += __shfl_xor(sum, mm);
      float inv = 1.f / sum;
      pbuf[w][r][l]      = p1 * inv;
      pbuf[w][r][l + 64] = p2 * inv;
    }
    __syncthreads();

    float acc[8];
#pragma unroll
    for (int r = 0; r < 8; ++r) acc[r] = 0.f;
    for (int j4 = 0; j4 < 32; ++j4) {
      f32x4 hv = *(const f32x4*)&hp_t[l * 128 + ((j4 ^ (l & 7)) << 2)];
#pragma unroll
      for (int r = 0; r < 8; ++r) {
        f32x4 pv = *(const f32x4*)&pbuf[w][r][j4 << 2];
        acc[r] += pv.x * hv.x + pv.y * hv.y + pv.z * hv.z + pv.w * hv.w;
      }
    }
    float* ob = out + (size_t)(b * SS + ibase) * NHID + head * 64 + l;
#pragma unroll
    for (int r = 0; r < 8; ++r) ob[(size_t)r * NHID] = acc[r];
    __syncthreads();
  }
}

// ---------------------------------------------------------------------------
// Final projection: Z[16384 x 64] = h @ Wz + bz.  64 rows per block.
// ---------------------------------------------------------------------------
__global__ __launch_bounds__(256, 1) void k_zgemm(
    const float* __restrict__ hmat, const float* __restrict__ Wz,
    const float* __restrict__ bz, float* __restrict__ Z)
{
  __shared__ __align__(16) float hrows[64 * 256];
  const int tid = threadIdx.x, w = tid >> 6, l = tid & 63;
  const int r0 = blockIdx.x * 64;
  const f32x4* src = (const f32x4*)(hmat + (size_t)r0 * NHID);
#pragma unroll
  for (int rep = 0; rep < 16; ++rep)
    ((f32x4*)hrows)[rep * 256 + tid] = src[rep * 256 + tid];
  __syncthreads();
  const float bzv = bz[l];
  const int rbase = w * 16;
#pragma unroll
  for (int pass = 0; pass < 4; ++pass) {
    float acc0 = 0.f, acc1 = 0.f, acc2 = 0.f, acc3 = 0.f;
    const float* h0 = &hrows[(rbase + pass * 4) * 256];
#pragma unroll 8
    for (int k = 0; k < 256; ++k) {
      float wv = Wz[k * 64 + l];
      acc0 += h0[k] * wv;
      acc1 += h0[256 + k] * wv;
      acc2 += h0[512 + k] * wv;
      acc3 += h0[768 + k] * wv;
    }
    float* zp = Z + (size_t)(r0 + rbase + pass * 4) * 64 + l;
    zp[0]   = acc0 + bzv;
    zp[64]  = acc1 + bzv;
    zp[128] = acc2 + bzv;
    zp[192] = acc3 + bzv;
  }
}

// ---------------------------------------------------------------------------
extern "C" void kernel_launch(void* const* d_in, const int* in_sizes, int n_in,
                              void* d_out, int out_size, void* d_ws, size_t ws_size,
                              hipStream_t stream)
{
  const float* x_set   = (const float*)d_in[0];
  const int*   adj     = (const int*)d_in[1];
  const float* W_in    = (const float*)d_in[2];
  const float* b_in    = (const float*)d_in[3];
  const float* ln_in_g = (const float*)d_in[4];
  const float* ln_in_b = (const float*)d_in[5];
  const float* Wg      = (const float*)d_in[6];
  const float* a_src   = (const float*)d_in[7];
  const float* a_dst   = (const float*)d_in[8];
  const float* a_edge  = (const float*)d_in[9];
  const float* We      = (const float*)d_in[10];
  const float* ln_g    = (const float*)d_in[11];
  const float* ln_b    = (const float*)d_in[12];
  const float* Wz      = (const float*)d_in[13];
  const float* bz      = (const float*)d_in[14];
  float* zout = (float*)d_out;

  const int M = BB * SS;          // 16384
  const int KPAD_IN = 2016;       // 63 * 32

  char* base = (char*)d_ws;
  size_t off = 0;
  auto alloc = [&](size_t bytes) { char* p = base + off; off += (bytes + 255) & ~(size_t)255; return p; };
  unsigned short* wt_in = (unsigned short*)alloc((size_t)NHID * KPAD_IN * 2);
  unsigned short* wgt   = (unsigned short*)alloc((size_t)NHID * NHID * 2);
  float* u1   = (float*)alloc(NHID * 4 * 4);
  float* u2   = (float*)alloc(NHID * 4 * 4);
  float* c1   = (float*)alloc((size_t)M * 4 * 4);
  float* c2   = (float*)alloc((size_t)M * 4 * 4);
  float* bufA = (float*)alloc((size_t)M * NHID * 4);
  float* bufB = (float*)alloc((size_t)M * NHID * 4);
  float* bufC = (float*)alloc((size_t)M * NHID * 4);

  // 1) W_in -> bf16 transposed+padded
  {
    int total = NHID * KPAD_IN;
    k_transconv<<<dim3((total + 255) / 256), dim3(256), 0, stream>>>(
        W_in, wt_in, GG, NHID, KPAD_IN);
  }
  // 2) input proj GEMM (+bias) -> bufA
  k_gemm<<<dim3(M / 128), dim3(512), 0, stream>>>(
      x_set, GG, GG, 63, wt_in, KPAD_IN, b_in, bufA);
  // 3) LN + GELU -> bufB (current h)
  k_ln_gelu<<<dim3(M / 4), dim3(256), 0, stream>>>(bufA, ln_in_g, ln_in_b, bufB, 1);

  for (int l = 0; l < 2; ++l) {
    const float* Wgl = Wg + (size_t)l * NHID * NHID;
    const float* Wel = We + (size_t)l * NHID * NHID;
    // a) Wg[l] -> bf16 transposed
    k_transconv<<<dim3((NHID * NHID + 255) / 256), dim3(256), 0, stream>>>(
        Wgl, wgt, NHID, NHID, NHID);
    // b) fold attention vectors
    k_proj<<<dim3(1), dim3(256), 0, stream>>>(
        Wgl, Wel, a_src + l * NHEAD * HDIM, a_dst + l * NHEAD * HDIM,
        a_edge + l * NHEAD * HDIM, u1, u2);
    // c) hp = h @ Wg[l] -> bufC
    k_gemm<<<dim3(M / 128), dim3(512), 0, stream>>>(
        bufB, NHID, NHID, 8, wgt, NHID, nullptr, bufC);
    // d) scores
    k_scores<<<dim3(M / 4), dim3(256), 0, stream>>>(bufB, u1, u2, c1, c2);
    // e) attention -> bufA
    k_attn<<<dim3(NHEAD, BB), dim3(256), 0, stream>>>(bufC, c1, c2, adj, bufA);
    // f) LN + GELU -> bufB
    k_ln_gelu<<<dim3(M / 4), dim3(256), 0, stream>>>(
        bufA, ln_g + l * NHID, ln_b + l * NHID, bufB, 1);
  }

  // 5) final projection
  k_zgemm<<<dim3(M / 64), dim3(256), 0, stream>>>(bufB, Wz, bz, zout);
}

// Round 3
// 336.491 us; speedup vs baseline: 1.2365x; 1.2365x over previous
//
#include <hip/hip_runtime.h>
#include <hip/hip_bf16.h>
#include <cstdint>
#include <cstddef>

// Problem constants
#define BB   128   // batch
#define SS   128   // set size
#define GG   2000  // genes (K of input proj)
#define NHID 256   // n_hidden
#define NHEAD 4
#define HDIM 64
#define NLAT 64
#define KPAD 2048  // padded K for input proj (2 x 1024 split-K)

typedef __attribute__((ext_vector_type(4))) float f32x4;
typedef __attribute__((ext_vector_type(8))) short short8;
typedef __attribute__((ext_vector_type(4))) short bfs4;
typedef __attribute__((ext_vector_type(8))) __bf16 bf8_t;

static __device__ __forceinline__ bf8_t as_bf8(short8 s){
  union { short8 s; bf8_t b; } u; u.s = s; return u.b;
}

static __device__ __forceinline__ unsigned short f2bf(float f){
  union { float f; unsigned u; } x; x.f = f;
  unsigned r = x.u + 0x7fffu + ((x.u >> 16) & 1u);
  return (unsigned short)(r >> 16);
}

#define GLOAD_LDS16(g, l) __builtin_amdgcn_global_load_lds( \
    (const __attribute__((address_space(1))) unsigned int*)(g), \
    (__attribute__((address_space(3))) unsigned int*)(l), 16, 0, 0)

// ---------------------------------------------------------------------------
// x_set (16384 x 2000 f32) -> Xb (16384 x 2048 bf16, zero-padded)
// ---------------------------------------------------------------------------
__global__ __launch_bounds__(256) void k_x2bf(
    const float* __restrict__ X, unsigned short* __restrict__ Xb)
{
  const int gid = blockIdx.x * 256 + threadIdx.x;   // short8 unit
  const int row = gid >> 8;                          // 256 units per row
  const int c8  = gid & 255;
  const int k0  = c8 << 3;
  short8 v;
  if (k0 < GG) {   // GG = 2000 = 250*8, so full or zero
    f32x4 a0 = *(const f32x4*)(X + (size_t)row * GG + k0);
    f32x4 a1 = *(const f32x4*)(X + (size_t)row * GG + k0 + 4);
    v[0]=(short)f2bf(a0.x); v[1]=(short)f2bf(a0.y); v[2]=(short)f2bf(a0.z); v[3]=(short)f2bf(a0.w);
    v[4]=(short)f2bf(a1.x); v[5]=(short)f2bf(a1.y); v[6]=(short)f2bf(a1.z); v[7]=(short)f2bf(a1.w);
  } else {
#pragma unroll
    for (int t = 0; t < 8; ++t) v[t] = 0;
  }
  *(short8*)(Xb + (size_t)row * KPAD + k0) = v;
}

// ---------------------------------------------------------------------------
// Transpose + convert + zero-pad: W (K x N, f32) -> Wt (N x Kpad, bf16)
// ---------------------------------------------------------------------------
__global__ __launch_bounds__(256) void k_transconv(
    const float* __restrict__ W, unsigned short* __restrict__ Wt,
    int K, int N, int Kpad)
{
  int idx = blockIdx.x * 256 + threadIdx.x;
  if (idx >= N * Kpad) return;
  int n = idx / Kpad, k = idx - n * Kpad;
  float v = (k < K) ? W[(size_t)k * N + n] : 0.f;
  Wt[idx] = f2bf(v);
}

// ---------------------------------------------------------------------------
// bf16 MFMA GEMM: Out[kz][M x 256 cols n0..n0+127] = A @ Bt^T  (f32 out)
//   A: bf16 [M][lda]; Bt: bf16 [256][ldb] (row n = column n of B).
//   BM=128, BN=128, BK=32; 256 thr = 4 waves (2x2 of 64x64).
//   Staging via global_load_lds (16B), double-buffered, frag-major LDS.
// ---------------------------------------------------------------------------
__global__ __launch_bounds__(256, 2) void k_gemm2(
    const unsigned short* __restrict__ A, int lda,
    const unsigned short* __restrict__ Bt, int ldb,
    float* __restrict__ Out, int nsteps, size_t psplit_stride)
{
  __shared__ __align__(16) unsigned short Ab[2][8][64][8];
  __shared__ __align__(16) unsigned short Bb[2][8][64][8];
  const int tid = threadIdx.x, l = tid & 63, w = tid >> 6;
  const int wr = w >> 1, wc = w & 1;
  const int m0 = blockIdx.x * 128, n0 = blockIdx.y * 128;
  Out += (size_t)blockIdx.z * psplit_stride;
  const int kbase0 = blockIdx.z * nsteps * 32;

  const int rA = l & 15, kg = l >> 4;
  const unsigned short* aB = A  + (size_t)(m0 + rA) * lda + kbase0 + kg * 8;
  const unsigned short* bB = Bt + (size_t)(n0 + rA) * ldb + kbase0 + kg * 8;

  f32x4 acc[4][4];
#pragma unroll
  for (int i = 0; i < 4; ++i)
#pragma unroll
    for (int j = 0; j < 4; ++j) acc[i][j] = (f32x4)(0.f);

  auto stage = [&](int buf, int koff) {
#pragma unroll
    for (int t = 0; t < 2; ++t) {
      const int ia = 2 * w + t;
      GLOAD_LDS16(aB + (size_t)(16 * ia) * lda + koff, &Ab[buf][ia][0][0]);
      GLOAD_LDS16(bB + (size_t)(16 * ia) * ldb + koff, &Bb[buf][ia][0][0]);
    }
  };

  stage(0, 0);
  __syncthreads();

  for (int s = 0; s < nsteps; ++s) {
    const int cur = s & 1;
    if (s + 1 < nsteps) stage(cur ^ 1, (s + 1) * 32);
    short8 af[4], bfv[4];
#pragma unroll
    for (int i = 0; i < 4; ++i) af[i]  = *(const short8*)&Ab[cur][4 * wr + i][l][0];
#pragma unroll
    for (int j = 0; j < 4; ++j) bfv[j] = *(const short8*)&Bb[cur][4 * wc + j][l][0];
#pragma unroll
    for (int i = 0; i < 4; ++i)
#pragma unroll
      for (int j = 0; j < 4; ++j)
        acc[i][j] = __builtin_amdgcn_mfma_f32_16x16x32_bf16(
            as_bf8(af[i]), as_bf8(bfv[j]), acc[i][j], 0, 0, 0);
    __syncthreads();
  }

  const int orow = m0 + (wr << 6) + ((l >> 4) << 2);
  const int ocol = n0 + (wc << 6) + (l & 15);
#pragma unroll
  for (int i = 0; i < 4; ++i)
#pragma unroll
    for (int j = 0; j < 4; ++j) {
      const int row = orow + i * 16, col = ocol + j * 16;
#pragma unroll
      for (int r = 0; r < 4; ++r)
        Out[(size_t)(row + r) * NHID + col] = acc[i][j][r];
    }
}

// ---------------------------------------------------------------------------
// Fused: x = X0 (+X1) (+bias) -> LayerNorm -> GELU -> bf16 h (+f32 h)
//        (+ scores c1 = h@u1, c2 = h@u2 when u != null)
// 16 rows per block (4 waves x 4 iters), one wave per row.
// ---------------------------------------------------------------------------
__global__ __launch_bounds__(256) void k_ln_fuse(
    const float* __restrict__ X0, const float* __restrict__ X1,
    const float* __restrict__ bias, const float* __restrict__ g,
    const float* __restrict__ b, unsigned short* __restrict__ out_bf,
    float* __restrict__ out_f32, const float* __restrict__ u,
    float* __restrict__ c1, float* __restrict__ c2)
{
  const int tid = threadIdx.x, l = tid & 63, w = tid >> 6;
  const f32x4 gg = *(const f32x4*)(g + l * 4);
  const f32x4 bb = *(const f32x4*)(b + l * 4);
  f32x4 bias4 = (f32x4)(0.f);
  if (bias) bias4 = *(const f32x4*)(bias + l * 4);
  f32x4 u1v[4], u2v[4];
  if (u) {
#pragma unroll
    for (int t = 0; t < 4; ++t) {
      u1v[t] = *(const f32x4*)(u + (size_t)(4 * l + t) * 4);
      u2v[t] = *(const f32x4*)(u + 1024 + (size_t)(4 * l + t) * 4);
    }
  }
  for (int it = 0; it < 4; ++it) {
    const int row = blockIdx.x * 16 + w * 4 + it;
    f32x4 x = *(const f32x4*)(X0 + (size_t)row * NHID + l * 4);
    if (X1) {
      f32x4 x1 = *(const f32x4*)(X1 + (size_t)row * NHID + l * 4);
      x.x += x1.x; x.y += x1.y; x.z += x1.z; x.w += x1.w;
    }
    x.x += bias4.x; x.y += bias4.y; x.z += bias4.z; x.w += bias4.w;
    float s  = x.x + x.y + x.z + x.w;
    float sq = x.x * x.x + x.y * x.y + x.z * x.z + x.w * x.w;
#pragma unroll
    for (int m = 1; m < 64; m <<= 1) { s += __shfl_xor(s, m); sq += __shfl_xor(sq, m); }
    const float mu   = s * (1.f / 256.f);
    const float var  = sq * (1.f / 256.f) - mu * mu;
    const float rstd = rsqrtf(var + 1e-5f);
    float y[4];
#pragma unroll
    for (int t = 0; t < 4; ++t) {
      float yy = (x[t] - mu) * rstd * gg[t] + bb[t];
      y[t] = 0.5f * yy * (1.f + erff(yy * 0.70710678118654752f));
    }
    if (out_bf) {
      bfs4 o;
#pragma unroll
      for (int t = 0; t < 4; ++t) o[t] = (short)f2bf(y[t]);
      *(bfs4*)(out_bf + (size_t)row * NHID + l * 4) = o;
    }
    if (out_f32) {
      f32x4 o; o.x = y[0]; o.y = y[1]; o.z = y[2]; o.w = y[3];
      *(f32x4*)(out_f32 + (size_t)row * NHID + l * 4) = o;
    }
    if (u) {
      float d1[4] = {0.f,0.f,0.f,0.f}, d2[4] = {0.f,0.f,0.f,0.f};
#pragma unroll
      for (int t = 0; t < 4; ++t)
#pragma unroll
        for (int h = 0; h < 4; ++h) {
          d1[h] += y[t] * u1v[t][h];
          d2[h] += y[t] * u2v[t][h];
        }
#pragma unroll
      for (int h = 0; h < 4; ++h) {
#pragma unroll
        for (int m = 1; m < 64; m <<= 1) {
          d1[h] += __shfl_xor(d1[h], m);
          d2[h] += __shfl_xor(d2[h], m);
        }
      }
      if (l == 0) {
#pragma unroll
        for (int h = 0; h < 4; ++h) {
          c1[(size_t)row * 4 + h] = d1[h];
          c2[(size_t)row * 4 + h] = d2[h];
        }
      }
    }
  }
}

// ---------------------------------------------------------------------------
// Fold a_src/a_dst/a_edge into u matrices (both layers; blockIdx.x = layer)
// ---------------------------------------------------------------------------
__global__ __launch_bounds__(256, 1) void k_proj(
    const float* __restrict__ Wg, const float* __restrict__ We,
    const float* __restrict__ asrc, const float* __restrict__ adst,
    const float* __restrict__ aedge, float* __restrict__ u)
{
  const int lyr = blockIdx.x;
  const int k = threadIdx.x;
  const float* Wgl = Wg + (size_t)lyr * NHID * NHID;
  const float* Wel = We + (size_t)lyr * NHID * NHID;
  float* u1 = u + (size_t)lyr * 2048;
  float* u2 = u1 + 1024;
#pragma unroll
  for (int h = 0; h < 4; ++h) {
    float ss = 0.f, sd = 0.f, se = 0.f;
    const float* wg  = Wgl + k * NHID + h * 64;
    const float* we  = Wel + k * NHID + h * 64;
    const float* pas = asrc + lyr * NHEAD * HDIM + h * 64;
    const float* pad_ = adst + lyr * NHEAD * HDIM + h * 64;
    const float* pae = aedge + lyr * NHEAD * HDIM + h * 64;
#pragma unroll 4
    for (int d = 0; d < 64; ++d) {
      ss += wg[d] * pas[d];
      sd += wg[d] * pad_[d];
      se += we[d] * pae[d];
    }
    u1[k * 4 + h] = ss + se;
    u2[k * 4 + h] = sd - se;
  }
}

// ---------------------------------------------------------------------------
// GAT attention, one block per (head, batch). S=128, HD=64.
// ---------------------------------------------------------------------------
__global__ __launch_bounds__(256, 1) void k_attn(
    const float* __restrict__ hp, const float* __restrict__ c1,
    const float* __restrict__ c2, const int* __restrict__ adj,
    float* __restrict__ out)
{
  __shared__ __align__(16) float hp_t[64 * 128];   // [d][j] swizzled
  __shared__ float s1[128], s2[128];
  __shared__ __align__(16) float pbuf[4][8][128];
  const int head = blockIdx.x, b = blockIdx.y;
  const int tid = threadIdx.x, w = tid >> 6, l = tid & 63;

  if (tid < 128) {
    int m = b * SS + tid;
    s1[tid] = c1[m * 4 + head];
    s2[tid] = c2[m * 4 + head];
  }
  const float* hpb = hp + (size_t)b * SS * NHID + head * 64 + l;
#pragma unroll 4
  for (int rep = 0; rep < 32; ++rep) {
    int j = w * 32 + rep;
    float v = hpb[(size_t)j * NHID];
    hp_t[l * 128 + (((j >> 2) ^ (l & 7)) << 2) + (j & 3)] = v;
  }
  __syncthreads();

  const int* adjb = adj + (size_t)b * SS * SS;
  for (int pass = 0; pass < 4; ++pass) {
    const int ibase = w * 32 + pass * 8;
#pragma unroll
    for (int r = 0; r < 8; ++r) {
      const int i = ibase + r;
      float s1v = s1[i];
      float x1 = s1v + s2[l];
      float x2 = s1v + s2[l + 64];
      x1 = x1 >= 0.f ? x1 : 0.2f * x1;
      x2 = x2 >= 0.f ? x2 : 0.2f * x2;
      int a1 = adjb[i * SS + l];
      int a2 = adjb[i * SS + 64 + l];
      float m1 = a1 ? x1 : -3.0e38f;
      float m2 = a2 ? x2 : -3.0e38f;
      float mx = fmaxf(m1, m2);
#pragma unroll
      for (int mm = 1; mm < 64; mm <<= 1) mx = fmaxf(mx, __shfl_xor(mx, mm));
      float p1 = a1 ? expf(x1 - mx) : 0.f;
      float p2 = a2 ? expf(x2 - mx) : 0.f;
      float sum = p1 + p2;
#pragma unroll
      for (int mm = 1; mm < 64; mm <<= 1) sum += __shfl_xor(sum, mm);
      float inv = 1.f / sum;
      pbuf[w][r][l]      = p1 * inv;
      pbuf[w][r][l + 64] = p2 * inv;
    }
    __syncthreads();

    float acc[8];
#pragma unroll
    for (int r = 0; r < 8; ++r) acc[r] = 0.f;
    for (int j4 = 0; j4 < 32; ++j4) {
      f32x4 hv = *(const f32x4*)&hp_t[l * 128 + ((j4 ^ (l & 7)) << 2)];
#pragma unroll
      for (int r = 0; r < 8; ++r) {
        f32x4 pv = *(const f32x4*)&pbuf[w][r][j4 << 2];
        acc[r] += pv.x * hv.x + pv.y * hv.y + pv.z * hv.z + pv.w * hv.w;
      }
    }
    float* ob = out + (size_t)(b * SS + ibase) * NHID + head * 64 + l;
#pragma unroll
    for (int r = 0; r < 8; ++r) ob[(size_t)r * NHID] = acc[r];
    __syncthreads();
  }
}

// ---------------------------------------------------------------------------
// Final projection: Z[16384 x 64] = h @ Wz + bz.  64 rows per block.
// ---------------------------------------------------------------------------
__global__ __launch_bounds__(256, 1) void k_zgemm(
    const float* __restrict__ hmat, const float* __restrict__ Wz,
    const float* __restrict__ bz, float* __restrict__ Z)
{
  __shared__ __align__(16) float hrows[64 * 256];
  const int tid = threadIdx.x, w = tid >> 6, l = tid & 63;
  const int r0 = blockIdx.x * 64;
  const f32x4* src = (const f32x4*)(hmat + (size_t)r0 * NHID);
#pragma unroll
  for (int rep = 0; rep < 16; ++rep)
    ((f32x4*)hrows)[rep * 256 + tid] = src[rep * 256 + tid];
  __syncthreads();
  const float bzv = bz[l];
  const int rbase = w * 16;
#pragma unroll
  for (int pass = 0; pass < 4; ++pass) {
    float acc0 = 0.f, acc1 = 0.f, acc2 = 0.f, acc3 = 0.f;
    const float* h0 = &hrows[(rbase + pass * 4) * 256];
#pragma unroll 8
    for (int k = 0; k < 256; ++k) {
      float wv = Wz[k * 64 + l];
      acc0 += h0[k] * wv;
      acc1 += h0[256 + k] * wv;
      acc2 += h0[512 + k] * wv;
      acc3 += h0[768 + k] * wv;
    }
    float* zp = Z + (size_t)(r0 + rbase + pass * 4) * 64 + l;
    zp[0]   = acc0 + bzv;
    zp[64]  = acc1 + bzv;
    zp[128] = acc2 + bzv;
    zp[192] = acc3 + bzv;
  }
}

// ---------------------------------------------------------------------------
extern "C" void kernel_launch(void* const* d_in, const int* in_sizes, int n_in,
                              void* d_out, int out_size, void* d_ws, size_t ws_size,
                              hipStream_t stream)
{
  const float* x_set   = (const float*)d_in[0];
  const int*   adj     = (const int*)d_in[1];
  const float* W_in    = (const float*)d_in[2];
  const float* b_in    = (const float*)d_in[3];
  const float* ln_in_g = (const float*)d_in[4];
  const float* ln_in_b = (const float*)d_in[5];
  const float* Wg      = (const float*)d_in[6];
  const float* a_src   = (const float*)d_in[7];
  const float* a_dst   = (const float*)d_in[8];
  const float* a_edge  = (const float*)d_in[9];
  const float* We      = (const float*)d_in[10];
  const float* ln_g    = (const float*)d_in[11];
  const float* ln_b    = (const float*)d_in[12];
  const float* Wz      = (const float*)d_in[13];
  const float* bz      = (const float*)d_in[14];
  float* zout = (float*)d_out;

  const int M = BB * SS;   // 16384

  char* base = (char*)d_ws;
  size_t off = 0;
  auto alloc = [&](size_t bytes) { char* p = base + off; off += (bytes + 255) & ~(size_t)255; return p; };
  unsigned short* Xb    = (unsigned short*)alloc((size_t)M * KPAD * 2);      // 67.1 MB
  float*          P     = (float*)alloc((size_t)M * NHID * 4 * 2);           // 33.6 MB (P0,P1)
  unsigned short* hbf   = (unsigned short*)alloc((size_t)M * NHID * 2);      // 8.4 MB
  unsigned short* wt_in = (unsigned short*)alloc((size_t)NHID * KPAD * 2);   // 1 MB
  unsigned short* wgt   = (unsigned short*)alloc((size_t)NHID * NHID * 2);   // 128 KB
  float*          u     = (float*)alloc(2 * 2048 * 4);
  float*          c1    = (float*)alloc((size_t)M * 4 * 4);
  float*          c2    = (float*)alloc((size_t)M * 4 * 4);
  // Xb region is dead after the input GEMM; reuse it for per-layer buffers.
  float* bufC = (float*)Xb;                       // hp  (16.8 MB)
  float* bufA = (float*)Xb + (size_t)M * NHID;    // attn out (16.8 MB)
  float* hfin = P;                                 // final h f32 (reuse P0)

  // 1) x_set -> bf16 padded
  k_x2bf<<<dim3((M * (KPAD / 8)) / 256), dim3(256), 0, stream>>>(x_set, Xb);
  // 2) W_in -> bf16 transposed+padded
  k_transconv<<<dim3((NHID * KPAD) / 256), dim3(256), 0, stream>>>(
      W_in, wt_in, GG, NHID, KPAD);
  // 3) fold attention vectors (both layers)
  k_proj<<<dim3(2), dim3(256), 0, stream>>>(Wg, We, a_src, a_dst, a_edge, u);
  // 4) input proj GEMM, split-K=2 -> P0,P1
  k_gemm2<<<dim3(M / 128, 2, 2), dim3(256), 0, stream>>>(
      Xb, KPAD, wt_in, KPAD, P, 32, (size_t)M * NHID);
  // 5) reduce + bias + LN + GELU -> hbf, + scores for layer 0
  k_ln_fuse<<<dim3(M / 16), dim3(256), 0, stream>>>(
      P, P + (size_t)M * NHID, b_in, ln_in_g, ln_in_b, hbf, nullptr,
      u, c1, c2);

  for (int l = 0; l < 2; ++l) {
    const float* Wgl = Wg + (size_t)l * NHID * NHID;
    // a) Wg[l] -> bf16 transposed
    k_transconv<<<dim3((NHID * NHID) / 256), dim3(256), 0, stream>>>(
        Wgl, wgt, NHID, NHID, NHID);
    // b) hp = h @ Wg[l] -> bufC
    k_gemm2<<<dim3(M / 128, 2, 1), dim3(256), 0, stream>>>(
        hbf, NHID, wgt, NHID, bufC, 8, 0);
    // c) attention -> bufA
    k_attn<<<dim3(NHEAD, BB), dim3(256), 0, stream>>>(bufC, c1, c2, adj, bufA);
    // d) LN + GELU (+ next-layer scores, or final f32 h)
    if (l == 0) {
      k_ln_fuse<<<dim3(M / 16), dim3(256), 0, stream>>>(
          bufA, nullptr, nullptr, ln_g, ln_b, hbf, nullptr,
          u + 2048, c1, c2);
    } else {
      k_ln_fuse<<<dim3(M / 16), dim3(256), 0, stream>>>(
          bufA, nullptr, nullptr, ln_g + NHID, ln_b + NHID, nullptr, hfin,
          nullptr, nullptr, nullptr);
    }
  }

  // 6) final projection
  k_zgemm<<<dim3(M / 64), dim3(256), 0, stream>>>(hfin, Wz, bz, zout);
}

// Round 4
// 223.727 us; speedup vs baseline: 1.8598x; 1.5040x over previous
//
#include <hip/hip_runtime.h>
#include <hip/hip_bf16.h>
#include <cstdint>
#include <cstddef>

// Problem constants
#define BB   128   // batch
#define SS   128   // set size
#define GG   2000  // genes (K of input proj)
#define NHID 256   // n_hidden
#define NHEAD 4
#define HDIM 64
#define NLAT 64
#define KPAD 2048  // padded K for input proj (2 x 1024 split-K)

typedef __attribute__((ext_vector_type(4))) float f32x4;
typedef __attribute__((ext_vector_type(8))) short short8;
typedef __attribute__((ext_vector_type(4))) short bfs4;
typedef __attribute__((ext_vector_type(8))) __bf16 bf8_t;

static __device__ __forceinline__ bf8_t as_bf8(short8 s){
  union { short8 s; bf8_t b; } u; u.s = s; return u.b;
}

static __device__ __forceinline__ unsigned short f2bf(float f){
  union { float f; unsigned u; } x; x.f = f;
  unsigned r = x.u + 0x7fffu + ((x.u >> 16) & 1u);
  return (unsigned short)(r >> 16);
}

#define GLOAD_LDS16(g, l) __builtin_amdgcn_global_load_lds( \
    (const __attribute__((address_space(1))) unsigned int*)(g), \
    (__attribute__((address_space(3))) unsigned int*)(l), 16, 0, 0)

// ---------------------------------------------------------------------------
// x_set (16384 x 2000 f32) -> Xb (16384 x 2048 bf16, zero-padded)
// ---------------------------------------------------------------------------
__global__ __launch_bounds__(256) void k_x2bf(
    const float* __restrict__ X, unsigned short* __restrict__ Xb)
{
  const int gid = blockIdx.x * 256 + threadIdx.x;   // short8 unit
  const int row = gid >> 8;                          // 256 units per row
  const int c8  = gid & 255;
  const int k0  = c8 << 3;
  short8 v;
  if (k0 < GG) {   // GG = 2000 = 250*8, so full or zero
    f32x4 a0 = *(const f32x4*)(X + (size_t)row * GG + k0);
    f32x4 a1 = *(const f32x4*)(X + (size_t)row * GG + k0 + 4);
    v[0]=(short)f2bf(a0.x); v[1]=(short)f2bf(a0.y); v[2]=(short)f2bf(a0.z); v[3]=(short)f2bf(a0.w);
    v[4]=(short)f2bf(a1.x); v[5]=(short)f2bf(a1.y); v[6]=(short)f2bf(a1.z); v[7]=(short)f2bf(a1.w);
  } else {
#pragma unroll
    for (int t = 0; t < 8; ++t) v[t] = 0;
  }
  *(short8*)(Xb + (size_t)row * KPAD + k0) = v;
}

// ---------------------------------------------------------------------------
// Transpose + convert + zero-pad: W (K x N, f32) -> Wt (N x Kpad, bf16)
// ---------------------------------------------------------------------------
__global__ __launch_bounds__(256) void k_transconv(
    const float* __restrict__ W, unsigned short* __restrict__ Wt,
    int K, int N, int Kpad)
{
  int idx = blockIdx.x * 256 + threadIdx.x;
  if (idx >= N * Kpad) return;
  int n = idx / Kpad, k = idx - n * Kpad;
  float v = (k < K) ? W[(size_t)k * N + n] : 0.f;
  Wt[idx] = f2bf(v);
}

// ---------------------------------------------------------------------------
// adj (B x S x S i32) -> bitmask (B*S*2 u64): one wave packs 64 ints.
// ---------------------------------------------------------------------------
__global__ __launch_bounds__(256) void k_adjpack(
    const int* __restrict__ adj, unsigned long long* __restrict__ abits)
{
  const int wid  = blockIdx.x * 4 + (threadIdx.x >> 6);
  const int lane = threadIdx.x & 63;
  int v = adj[(size_t)wid * 64 + lane];
  unsigned long long m = __ballot(v != 0);
  if (lane == 0) abits[wid] = m;
}

// ---------------------------------------------------------------------------
// bf16 MFMA GEMM: Out[kz][M x 256] = A @ Bt^T  (f32 and/or bf16 out)
//   BM=128, BN=128, BK=32; 256 thr = 4 waves (2x2 of 64x64).
// ---------------------------------------------------------------------------
__global__ __launch_bounds__(256, 2) void k_gemm2(
    const unsigned short* __restrict__ A, int lda,
    const unsigned short* __restrict__ Bt, int ldb,
    float* __restrict__ Out, unsigned short* __restrict__ Outbf,
    int nsteps, size_t psplit_stride)
{
  __shared__ __align__(16) unsigned short Ab[2][8][64][8];
  __shared__ __align__(16) unsigned short Bb[2][8][64][8];
  const int tid = threadIdx.x, l = tid & 63, w = tid >> 6;
  const int wr = w >> 1, wc = w & 1;
  const int m0 = blockIdx.x * 128, n0 = blockIdx.y * 128;
  if (Out) Out += (size_t)blockIdx.z * psplit_stride;
  const int kbase0 = blockIdx.z * nsteps * 32;

  const int rA = l & 15, kg = l >> 4;
  const unsigned short* aB = A  + (size_t)(m0 + rA) * lda + kbase0 + kg * 8;
  const unsigned short* bB = Bt + (size_t)(n0 + rA) * ldb + kbase0 + kg * 8;

  f32x4 acc[4][4];
#pragma unroll
  for (int i = 0; i < 4; ++i)
#pragma unroll
    for (int j = 0; j < 4; ++j) acc[i][j] = (f32x4)(0.f);

  auto stage = [&](int buf, int koff) {
#pragma unroll
    for (int t = 0; t < 2; ++t) {
      const int ia = 2 * w + t;
      GLOAD_LDS16(aB + (size_t)(16 * ia) * lda + koff, &Ab[buf][ia][0][0]);
      GLOAD_LDS16(bB + (size_t)(16 * ia) * ldb + koff, &Bb[buf][ia][0][0]);
    }
  };

  stage(0, 0);
  __syncthreads();

  for (int s = 0; s < nsteps; ++s) {
    const int cur = s & 1;
    if (s + 1 < nsteps) stage(cur ^ 1, (s + 1) * 32);
    short8 af[4], bfv[4];
#pragma unroll
    for (int i = 0; i < 4; ++i) af[i]  = *(const short8*)&Ab[cur][4 * wr + i][l][0];
#pragma unroll
    for (int j = 0; j < 4; ++j) bfv[j] = *(const short8*)&Bb[cur][4 * wc + j][l][0];
#pragma unroll
    for (int i = 0; i < 4; ++i)
#pragma unroll
      for (int j = 0; j < 4; ++j)
        acc[i][j] = __builtin_amdgcn_mfma_f32_16x16x32_bf16(
            as_bf8(af[i]), as_bf8(bfv[j]), acc[i][j], 0, 0, 0);
    __syncthreads();
  }

  const int orow = m0 + (wr << 6) + ((l >> 4) << 2);
  const int ocol = n0 + (wc << 6) + (l & 15);
#pragma unroll
  for (int i = 0; i < 4; ++i)
#pragma unroll
    for (int j = 0; j < 4; ++j) {
      const int row = orow + i * 16, col = ocol + j * 16;
#pragma unroll
      for (int r = 0; r < 4; ++r) {
        if (Out)   Out[(size_t)(row + r) * NHID + col] = acc[i][j][r];
        if (Outbf) Outbf[(size_t)(row + r) * NHID + col] = f2bf(acc[i][j][r]);
      }
    }
}

// ---------------------------------------------------------------------------
// Fused: x = X0 (+X1) (+bias) -> LayerNorm -> GELU -> bf16 h (+f32 h)
//        (+ scores c1 = h@u1, c2 = h@u2 when u != null)
// ---------------------------------------------------------------------------
__global__ __launch_bounds__(256) void k_ln_fuse(
    const float* __restrict__ X0, const float* __restrict__ X1,
    const float* __restrict__ bias, const float* __restrict__ g,
    const float* __restrict__ b, unsigned short* __restrict__ out_bf,
    float* __restrict__ out_f32, const float* __restrict__ u,
    float* __restrict__ c1, float* __restrict__ c2)
{
  const int tid = threadIdx.x, l = tid & 63, w = tid >> 6;
  const f32x4 gg = *(const f32x4*)(g + l * 4);
  const f32x4 bb = *(const f32x4*)(b + l * 4);
  f32x4 bias4 = (f32x4)(0.f);
  if (bias) bias4 = *(const f32x4*)(bias + l * 4);
  f32x4 u1v[4], u2v[4];
  if (u) {
#pragma unroll
    for (int t = 0; t < 4; ++t) {
      u1v[t] = *(const f32x4*)(u + (size_t)(4 * l + t) * 4);
      u2v[t] = *(const f32x4*)(u + 1024 + (size_t)(4 * l + t) * 4);
    }
  }
  for (int it = 0; it < 4; ++it) {
    const int row = blockIdx.x * 16 + w * 4 + it;
    f32x4 x = *(const f32x4*)(X0 + (size_t)row * NHID + l * 4);
    if (X1) {
      f32x4 x1 = *(const f32x4*)(X1 + (size_t)row * NHID + l * 4);
      x.x += x1.x; x.y += x1.y; x.z += x1.z; x.w += x1.w;
    }
    x.x += bias4.x; x.y += bias4.y; x.z += bias4.z; x.w += bias4.w;
    float s  = x.x + x.y + x.z + x.w;
    float sq = x.x * x.x + x.y * x.y + x.z * x.z + x.w * x.w;
#pragma unroll
    for (int m = 1; m < 64; m <<= 1) { s += __shfl_xor(s, m); sq += __shfl_xor(sq, m); }
    const float mu   = s * (1.f / 256.f);
    const float var  = sq * (1.f / 256.f) - mu * mu;
    const float rstd = rsqrtf(var + 1e-5f);
    float y[4];
#pragma unroll
    for (int t = 0; t < 4; ++t) {
      float yy = (x[t] - mu) * rstd * gg[t] + bb[t];
      y[t] = 0.5f * yy * (1.f + erff(yy * 0.70710678118654752f));
    }
    if (out_bf) {
      bfs4 o;
#pragma unroll
      for (int t = 0; t < 4; ++t) o[t] = (short)f2bf(y[t]);
      *(bfs4*)(out_bf + (size_t)row * NHID + l * 4) = o;
    }
    if (out_f32) {
      f32x4 o; o.x = y[0]; o.y = y[1]; o.z = y[2]; o.w = y[3];
      *(f32x4*)(out_f32 + (size_t)row * NHID + l * 4) = o;
    }
    if (u) {
      float d1[4] = {0.f,0.f,0.f,0.f}, d2[4] = {0.f,0.f,0.f,0.f};
#pragma unroll
      for (int t = 0; t < 4; ++t)
#pragma unroll
        for (int h = 0; h < 4; ++h) {
          d1[h] += y[t] * u1v[t][h];
          d2[h] += y[t] * u2v[t][h];
        }
#pragma unroll
      for (int h = 0; h < 4; ++h) {
#pragma unroll
        for (int m = 1; m < 64; m <<= 1) {
          d1[h] += __shfl_xor(d1[h], m);
          d2[h] += __shfl_xor(d2[h], m);
        }
      }
      if (l == 0) {
#pragma unroll
        for (int h = 0; h < 4; ++h) {
          c1[(size_t)row * 4 + h] = d1[h];
          c2[(size_t)row * 4 + h] = d2[h];
        }
      }
    }
  }
}

// ---------------------------------------------------------------------------
// Fold a_src/a_dst/a_edge into u matrices (both layers; blockIdx.x = layer)
// ---------------------------------------------------------------------------
__global__ __launch_bounds__(256, 1) void k_proj(
    const float* __restrict__ Wg, const float* __restrict__ We,
    const float* __restrict__ asrc, const float* __restrict__ adst,
    const float* __restrict__ aedge, float* __restrict__ u)
{
  const int lyr = blockIdx.x;
  const int k = threadIdx.x;
  const float* Wgl = Wg + (size_t)lyr * NHID * NHID;
  const float* Wel = We + (size_t)lyr * NHID * NHID;
  float* u1 = u + (size_t)lyr * 2048;
  float* u2 = u1 + 1024;
#pragma unroll
  for (int h = 0; h < 4; ++h) {
    float ss = 0.f, sd = 0.f, se = 0.f;
    const float* wg  = Wgl + k * NHID + h * 64;
    const float* we  = Wel + k * NHID + h * 64;
    const float* pas = asrc + lyr * NHEAD * HDIM + h * 64;
    const float* pad_ = adst + lyr * NHEAD * HDIM + h * 64;
    const float* pae = aedge + lyr * NHEAD * HDIM + h * 64;
#pragma unroll 4
    for (int d = 0; d < 64; ++d) {
      ss += wg[d] * pas[d];
      sd += wg[d] * pad_[d];
      se += we[d] * pae[d];
    }
    u1[k * 4 + h] = ss + se;
    u2[k * 4 + h] = sd - se;
  }
}

// ---------------------------------------------------------------------------
// GAT attention v2: block per (head, b). Lane-per-row softmax (no cross-lane
// reduce), bitmask adjacency, PV via MFMA with P/hp in fragment-layout LDS.
// ---------------------------------------------------------------------------
__global__ __launch_bounds__(256) void k_attn2(
    const unsigned short* __restrict__ hpbf, const float* __restrict__ c1,
    const float* __restrict__ c2, const unsigned long long* __restrict__ abits,
    float* __restrict__ out)
{
  __shared__ __align__(16) unsigned short Pb[4][8][64][8];   // 32 KB A-frags
  __shared__ __align__(16) unsigned short Vb[4][4][64][8];   // 16 KB B-frags
  __shared__ float s1[128], s2[128];
  __shared__ float mbuf[2][128], sbuf[2][128], invsum[128];
  const int head = blockIdx.x, b = blockIdx.y;
  const int tid = threadIdx.x;

  if (tid < 128) {
    const int m = b * SS + tid;
    s1[tid] = c1[m * 4 + head];
    s2[tid] = c2[m * 4 + head];
  }
  // stage hp (bf16 [j][256]) -> Vb B-fragment layout
  {
    const unsigned short* hb = hpbf + (size_t)b * SS * NHID + head * 64;
#pragma unroll
    for (int q = 0; q < 4; ++q) {
      const int task = tid + 256 * q;
      const int l = task & 63, tile = task >> 6;    // 16 tiles
      const int kstep = tile >> 2, nt = tile & 3;
      const int j0 = kstep * 32 + (l >> 4) * 8;
      const int d  = nt * 16 + (l & 15);
      short8 v;
#pragma unroll
      for (int e = 0; e < 8; ++e)
        v[e] = (short)hb[(size_t)(j0 + e) * NHID + d];
      *(short8*)&Vb[kstep][nt][l][0] = v;
    }
  }
  __syncthreads();

  const int i = tid & 127, half = tid >> 7;
  const float s1v = s1[i];
  const unsigned long long bits = abits[((size_t)b * SS + i) * 2 + half];

  // pass 1: row-half max (serial per thread, 4 independent chains)
  float ma[4] = {-3.0e38f, -3.0e38f, -3.0e38f, -3.0e38f};
#pragma unroll
  for (int jl = 0; jl < 64; ++jl) {
    float x  = s1v + s2[half * 64 + jl];
    float lk = fmaxf(x, 0.2f * x);                  // LeakyReLU(0.2)
    float xm = ((bits >> jl) & 1ull) ? lk : -3.0e38f;
    ma[jl & 3] = fmaxf(ma[jl & 3], xm);
  }
  mbuf[half][i] = fmaxf(fmaxf(ma[0], ma[1]), fmaxf(ma[2], ma[3]));
  __syncthreads();
  const float mrow = fmaxf(mbuf[0][i], mbuf[1][i]);

  // pass 2: exp, sum, write P fragments (unnormalized, bf16)
  float sa[4] = {0.f, 0.f, 0.f, 0.f};
#pragma unroll
  for (int grp = 0; grp < 8; ++grp) {
    short8 pv;
#pragma unroll
    for (int e = 0; e < 8; ++e) {
      const int jl = grp * 8 + e;
      float x  = s1v + s2[half * 64 + jl];
      float lk = fmaxf(x, 0.2f * x);
      float xm = ((bits >> jl) & 1ull) ? lk : -3.0e38f;
      float p  = exp2f((xm - mrow) * 1.4426950408889634f);
      sa[e & 3] += p;
      pv[e] = (short)f2bf(p);
    }
    const int j = half * 64 + grp * 8;
    const int kstep = j >> 5, g = (j >> 3) & 3;
    *(short8*)&Pb[kstep][i >> 4][(g << 4) | (i & 15)][0] = pv;
  }
  sbuf[half][i] = (sa[0] + sa[1]) + (sa[2] + sa[3]);
  __syncthreads();
  if (tid < 128) invsum[tid] = 1.f / (sbuf[0][tid] + sbuf[1][tid]);
  __syncthreads();

  // phase 3: PV via MFMA. wave w owns output rows [w*32, w*32+32)
  const int w = tid >> 6, l = tid & 63;
  f32x4 acc[2][4];
#pragma unroll
  for (int ii = 0; ii < 2; ++ii)
#pragma unroll
    for (int nt = 0; nt < 4; ++nt) acc[ii][nt] = (f32x4)(0.f);
#pragma unroll
  for (int kstep = 0; kstep < 4; ++kstep) {
    short8 bv[4];
#pragma unroll
    for (int nt = 0; nt < 4; ++nt) bv[nt] = *(const short8*)&Vb[kstep][nt][l][0];
#pragma unroll
    for (int ii = 0; ii < 2; ++ii) {
      short8 af = *(const short8*)&Pb[kstep][2 * w + ii][l][0];
#pragma unroll
      for (int nt = 0; nt < 4; ++nt)
        acc[ii][nt] = __builtin_amdgcn_mfma_f32_16x16x32_bf16(
            as_bf8(af), as_bf8(bv[nt]), acc[ii][nt], 0, 0, 0);
    }
  }

  // epilogue: normalize by 1/sum and store f32
  float* ob = out + (size_t)(b * SS) * NHID + head * 64;
#pragma unroll
  for (int ii = 0; ii < 2; ++ii) {
    const int it = 2 * w + ii;
#pragma unroll
    for (int r = 0; r < 4; ++r) {
      const int row = it * 16 + (l >> 4) * 4 + r;
      const float inv = invsum[row];
#pragma unroll
      for (int nt = 0; nt < 4; ++nt)
        ob[(size_t)row * NHID + nt * 16 + (l & 15)] = acc[ii][nt][r] * inv;
    }
  }
}

// ---------------------------------------------------------------------------
// Final projection: Z[16384 x 64] = h @ Wz + bz.  64 rows per block.
// ---------------------------------------------------------------------------
__global__ __launch_bounds__(256, 1) void k_zgemm(
    const float* __restrict__ hmat, const float* __restrict__ Wz,
    const float* __restrict__ bz, float* __restrict__ Z)
{
  __shared__ __align__(16) float hrows[64 * 256];
  const int tid = threadIdx.x, w = tid >> 6, l = tid & 63;
  const int r0 = blockIdx.x * 64;
  const f32x4* src = (const f32x4*)(hmat + (size_t)r0 * NHID);
#pragma unroll
  for (int rep = 0; rep < 16; ++rep)
    ((f32x4*)hrows)[rep * 256 + tid] = src[rep * 256 + tid];
  __syncthreads();
  const float bzv = bz[l];
  const int rbase = w * 16;
#pragma unroll
  for (int pass = 0; pass < 4; ++pass) {
    float acc0 = 0.f, acc1 = 0.f, acc2 = 0.f, acc3 = 0.f;
    const float* h0 = &hrows[(rbase + pass * 4) * 256];
#pragma unroll 8
    for (int k = 0; k < 256; ++k) {
      float wv = Wz[k * 64 + l];
      acc0 += h0[k] * wv;
      acc1 += h0[256 + k] * wv;
      acc2 += h0[512 + k] * wv;
      acc3 += h0[768 + k] * wv;
    }
    float* zp = Z + (size_t)(r0 + rbase + pass * 4) * 64 + l;
    zp[0]   = acc0 + bzv;
    zp[64]  = acc1 + bzv;
    zp[128] = acc2 + bzv;
    zp[192] = acc3 + bzv;
  }
}

// ---------------------------------------------------------------------------
extern "C" void kernel_launch(void* const* d_in, const int* in_sizes, int n_in,
                              void* d_out, int out_size, void* d_ws, size_t ws_size,
                              hipStream_t stream)
{
  const float* x_set   = (const float*)d_in[0];
  const int*   adj     = (const int*)d_in[1];
  const float* W_in    = (const float*)d_in[2];
  const float* b_in    = (const float*)d_in[3];
  const float* ln_in_g = (const float*)d_in[4];
  const float* ln_in_b = (const float*)d_in[5];
  const float* Wg      = (const float*)d_in[6];
  const float* a_src   = (const float*)d_in[7];
  const float* a_dst   = (const float*)d_in[8];
  const float* a_edge  = (const float*)d_in[9];
  const float* We      = (const float*)d_in[10];
  const float* ln_g    = (const float*)d_in[11];
  const float* ln_b    = (const float*)d_in[12];
  const float* Wz      = (const float*)d_in[13];
  const float* bz      = (const float*)d_in[14];
  float* zout = (float*)d_out;

  const int M = BB * SS;   // 16384

  char* base = (char*)d_ws;
  size_t off = 0;
  auto alloc = [&](size_t bytes) { char* p = base + off; off += (bytes + 255) & ~(size_t)255; return p; };
  unsigned short* Xb    = (unsigned short*)alloc((size_t)M * KPAD * 2);      // 67.1 MB
  float*          P     = (float*)alloc((size_t)M * NHID * 4 * 2);           // 33.6 MB (P0,P1)
  unsigned short* hbf   = (unsigned short*)alloc((size_t)M * NHID * 2);      // 8.4 MB
  unsigned short* wt_in = (unsigned short*)alloc((size_t)NHID * KPAD * 2);   // 1 MB
  unsigned short* wgt   = (unsigned short*)alloc((size_t)NHID * NHID * 2);   // 128 KB
  float*          u     = (float*)alloc(2 * 2048 * 4);
  float*          c1    = (float*)alloc((size_t)M * 4 * 4);
  float*          c2    = (float*)alloc((size_t)M * 4 * 4);
  unsigned long long* abits = (unsigned long long*)alloc((size_t)BB * SS * 2 * 8); // 256 KB
  // Xb region is dead after the input GEMM; reuse it for per-layer buffers.
  unsigned short* hpbf = Xb;                       // hp bf16 (8.4 MB)
  float* bufA = (float*)Xb + (size_t)M * NHID;     // attn out f32 (16.8 MB)
  float* hfin = P;                                 // final h f32 (reuse P0)

  // 1) x_set -> bf16 padded
  k_x2bf<<<dim3((M * (KPAD / 8)) / 256), dim3(256), 0, stream>>>(x_set, Xb);
  // 2) W_in -> bf16 transposed+padded
  k_transconv<<<dim3((NHID * KPAD) / 256), dim3(256), 0, stream>>>(
      W_in, wt_in, GG, NHID, KPAD);
  // 3) fold attention vectors (both layers); pack adj bitmask
  k_proj<<<dim3(2), dim3(256), 0, stream>>>(Wg, We, a_src, a_dst, a_edge, u);
  k_adjpack<<<dim3(BB * SS * 2 / 4), dim3(256), 0, stream>>>(adj, abits);
  // 4) input proj GEMM, split-K=2 -> P0,P1
  k_gemm2<<<dim3(M / 128, 2, 2), dim3(256), 0, stream>>>(
      Xb, KPAD, wt_in, KPAD, P, nullptr, 32, (size_t)M * NHID);
  // 5) reduce + bias + LN + GELU -> hbf, + scores for layer 0
  k_ln_fuse<<<dim3(M / 16), dim3(256), 0, stream>>>(
      P, P + (size_t)M * NHID, b_in, ln_in_g, ln_in_b, hbf, nullptr,
      u, c1, c2);

  for (int l = 0; l < 2; ++l) {
    const float* Wgl = Wg + (size_t)l * NHID * NHID;
    // a) Wg[l] -> bf16 transposed
    k_transconv<<<dim3((NHID * NHID) / 256), dim3(256), 0, stream>>>(
        Wgl, wgt, NHID, NHID, NHID);
    // b) hp = h @ Wg[l] -> hpbf (bf16)
    k_gemm2<<<dim3(M / 128, 2, 1), dim3(256), 0, stream>>>(
        hbf, NHID, wgt, NHID, nullptr, hpbf, 8, 0);
    // c) attention -> bufA
    k_attn2<<<dim3(NHEAD, BB), dim3(256), 0, stream>>>(
        hpbf, c1, c2, abits, bufA);
    // d) LN + GELU (+ next-layer scores, or final f32 h)
    if (l == 0) {
      k_ln_fuse<<<dim3(M / 16), dim3(256), 0, stream>>>(
          bufA, nullptr, nullptr, ln_g, ln_b, hbf, nullptr,
          u + 2048, c1, c2);
    } else {
      k_ln_fuse<<<dim3(M / 16), dim3(256), 0, stream>>>(
          bufA, nullptr, nullptr, ln_g + NHID, ln_b + NHID, nullptr, hfin,
          nullptr, nullptr, nullptr);
    }
  }

  // 6) final projection
  k_zgemm<<<dim3(M / 64), dim3(256), 0, stream>>>(hfin, Wz, bz, zout);
}